// Round 17
// baseline (517.393 us; speedup 1.0000x reference)
//
#include <hip/hip_runtime.h>
#include <hip/hip_bf16.h>
#include <stdint.h>

#define C_    512
#define T_    24
#define HWSZ  1024
#define NN    4096
#define JTOT  98304   // T_*NN
#define EPSV  1e-5f

typedef short short8 __attribute__((ext_vector_type(8)));
typedef short short4v __attribute__((ext_vector_type(4)));
typedef float f32x4 __attribute__((ext_vector_type(4)));
typedef float f32x2 __attribute__((ext_vector_type(2)));
typedef __bf16 bf16x2 __attribute__((ext_vector_type(2)));

typedef __attribute__((address_space(1))) const uint32_t glob_u32;
typedef __attribute__((address_space(3))) uint32_t lds_u32;

#if __has_builtin(__builtin_amdgcn_fdot2_f32_bf16)
#define HAS_DOT2 1
#else
#define HAS_DOT2 0
#endif

__device__ __forceinline__ unsigned short f2bf(float f) {
  union { float f; unsigned u; } v; v.f = f;
  unsigned r = v.u + 0x7fffu + ((v.u >> 16) & 1u);
  return (unsigned short)(r >> 16);
}
__device__ __forceinline__ float bf2f(unsigned short b) {
  union { unsigned u; float f; } v; v.u = ((unsigned)b) << 16;
  return v.f;
}
__device__ __forceinline__ float bflo(uint32_t u) {
  union { unsigned u; float f; } v; v.u = u << 16; return v.f;
}
__device__ __forceinline__ float bfhi(uint32_t u) {
  union { unsigned u; float f; } v; v.u = u & 0xffff0000u; return v.f;
}
__device__ __forceinline__ uint32_t pkbf(float a, float b) {
  return (uint32_t)f2bf(a) | ((uint32_t)f2bf(b) << 16);
}
__device__ __forceinline__ bf16x2 asbf2(uint32_t u) {
  union { uint32_t u; bf16x2 v; } c; c.u = u; return c.v;
}

__device__ __forceinline__ void gload_lds16(const void* g, void* l) {
  __builtin_amdgcn_global_load_lds((glob_u32*)g, (lds_u32*)l, 16, 0, 0);
}

// ---------------- K0: weight f32 -> bf16 ----------------
__global__ void k_cvt(const float* __restrict__ qkvw, const float* __restrict__ projw,
                      unsigned short* __restrict__ qkvw_bf, unsigned short* __restrict__ projw_bf) {
  int i = blockIdx.x * 256 + threadIdx.x;
  if (i < 786432) qkvw_bf[i] = f2bf(qkvw[i]);
  if (i < 262144) projw_bf[i] = f2bf(projw[i]);
}

// ---------------- K1a: GroupNorm stats ----------------
__global__ __launch_bounds__(256) void k_stats(const float* __restrict__ x,
                                               float* __restrict__ mean, float* __restrict__ rstd) {
  int bid = blockIdx.x;
  int g = bid & 31, hwt = (bid >> 5) & 15, b = bid >> 9;
  int tid = threadIdx.x, lane = tid & 63, grp = tid >> 6;
  int hw = hwt * 64 + lane;
  float s = 0.f, sq = 0.f;
  for (int ct = grp; ct < 384; ct += 4) {
    int c = g * 16 + ct / 24;
    int t = ct % 24;
    float v = x[((size_t)((b * 512 + c) * 24 + t) << 10) + hw];
    s += v; sq += v * v;
  }
  __shared__ float ls[4][64], lq[4][64];
  ls[grp][lane] = s; lq[grp][lane] = sq;
  __syncthreads();
  if (tid < 64) {
    float S = ls[0][tid] + ls[1][tid] + ls[2][tid] + ls[3][tid];
    float Q = lq[0][tid] + lq[1][tid] + lq[2][tid] + lq[3][tid];
    float m = S * (1.f / 384.f);
    float var = Q * (1.f / 384.f) - m * m;
    int n = b * HWSZ + hwt * 64 + tid;
    mean[n * 32 + g] = m;
    rstd[n * 32 + g] = rsqrtf(var + EPSV);
  }
}

// ---------------- K1b: normalize + transpose to Xn[j][c] bf16 (v3) ----------------
__global__ __launch_bounds__(256) void k_norm(const float* __restrict__ x,
                                              const float* __restrict__ mean, const float* __restrict__ rstd,
                                              const float* __restrict__ gnw, const float* __restrict__ gnb,
                                              unsigned short* __restrict__ xn) {
  __shared__ unsigned short xs[64][260];
  const int bid = blockIdx.x;
  const int hwt = bid & 15;
  const int chalf = (bid >> 4) & 1;
  const int tb = bid >> 5;
  const int t = tb % 24, b = tb / 24;
  const int hw0 = hwt * 64;
  const int tid = threadIdx.x;
  const int w = tid >> 6, lane = tid & 63;

  const int cslot = w * 4 + (lane >> 4);
  const int hwr = (lane & 15) * 4;
#pragma unroll
  for (int k = 0; k < 8; ++k) {
    const int crel = k * 32 + cslot * 2;
    const int c = chalf * 256 + crel;
    const float4 v0 = *reinterpret_cast<const float4*>(
        &x[(((size_t)(b * 512 + c) * 24 + t) << 10) + hw0 + hwr]);
    const float4 v1 = *reinterpret_cast<const float4*>(
        &x[(((size_t)(b * 512 + c + 1) * 24 + t) << 10) + hw0 + hwr]);
    *reinterpret_cast<uint32_t*>(&xs[hwr + 0][crel]) = pkbf(v0.x, v1.x);
    *reinterpret_cast<uint32_t*>(&xs[hwr + 1][crel]) = pkbf(v0.y, v1.y);
    *reinterpret_cast<uint32_t*>(&xs[hwr + 2][crel]) = pkbf(v0.z, v1.z);
    *reinterpret_cast<uint32_t*>(&xs[hwr + 3][crel]) = pkbf(v0.w, v1.w);
  }

  const int crel8 = (lane & 31) * 8;
  const int c8 = chalf * 256 + crel8;
  const int g = c8 >> 4;
  float gw[8], gb[8];
#pragma unroll
  for (int i = 0; i < 8; ++i) { gw[i] = gnw[c8 + i]; gb[i] = gnb[c8 + i]; }
  float mm[8], rr[8];
#pragma unroll
  for (int p = 0; p < 8; ++p) {
    const int nrel = (p * 4 + w) * 2 + (lane >> 5);
    const int ng = b * HWSZ + hw0 + nrel;
    mm[p] = mean[ng * 32 + g];
    rr[p] = rstd[ng * 32 + g];
  }
  __syncthreads();

#pragma unroll
  for (int p = 0; p < 8; ++p) {
    const int nrel = (p * 4 + w) * 2 + (lane >> 5);
    const short4v lo = *reinterpret_cast<const short4v*>(&xs[nrel][crel8]);
    const short4v hi = *reinterpret_cast<const short4v*>(&xs[nrel][crel8 + 4]);
    float y[8];
#pragma unroll
    for (int i = 0; i < 4; ++i) {
      y[i]     = (bf2f((unsigned short)lo[i]) - mm[p]) * rr[p] * gw[i]     + gb[i];
      y[i + 4] = (bf2f((unsigned short)hi[i]) - mm[p]) * rr[p] * gw[i + 4] + gb[i + 4];
    }
    uint4 wv;
    wv.x = pkbf(y[0], y[1]);
    wv.y = pkbf(y[2], y[3]);
    wv.z = pkbf(y[4], y[5]);
    wv.w = pkbf(y[6], y[7]);
    const size_t j = (size_t)t * NN + b * HWSZ + hw0 + nrel;
    *reinterpret_cast<uint4*>(&xn[j * C_ + c8]) = wv;
  }
}

// ---------------- K2: 256x256 8-phase bf16 MFMA GEMM (QKV; dp-interleaved packed out) ----------------
// Output: qkvP[mat 3][h 8][chunk 8][t 24][n 4096][dp 4] u32 (bf16 pair per u32).
#define STAGE8(mat, half, tile, Gptr, row0)                                           \
  {                                                                                   \
    unsigned short* _l = &lds[(((tile) & 1) * 2 + (mat))][half][(w * 2) * 512];       \
    const unsigned short* _g = (Gptr) +                                               \
        (size_t)((row0) + (half) * 128 + (w * 2) * 8 + srow) * 512 +                  \
        (tile) * 64 + sslot * 8;                                                      \
    gload_lds16(_g, _l);                                                              \
    gload_lds16(_g + 8 * 512, _l + 512);                                              \
  }

__global__ __launch_bounds__(512, 2) void k_gemm8(
    const unsigned short* __restrict__ A,   // [1536][512] bf16
    const unsigned short* __restrict__ B,   // [JTOT][512] bf16
    const float* __restrict__ bias,         // [1536]
    uint32_t* __restrict__ outP) {          // packed qkvP
  __shared__ __attribute__((aligned(16))) unsigned short lds[4][2][8192];
  const int bid = blockIdx.x;
  const int cpx = 2304 >> 3;
  const int lid = (bid & 7) * cpx + (bid >> 3);
  const int mt = lid % 6, jt = lid / 6;
  const int m0 = mt * 256, j0 = jt * 256;
  const int tid = threadIdx.x;
  const int w = tid >> 6, lane = tid & 63;
  const int l16 = lane & 15, lqq = lane >> 4;
  const int wm = w >> 2, wn = w & 3;
  const int srow = lane >> 3;
  const int sslot = (lane & 7) ^ srow;
  const int k0off = l16 * 64 + ((lqq ^ (l16 & 7)) * 8);
  const int k1off = l16 * 64 + (((lqq + 4) ^ (l16 & 7)) * 8);

  f32x4 acc[8][4];
#pragma unroll
  for (int i = 0; i < 8; ++i)
#pragma unroll
    for (int j = 0; j < 4; ++j) acc[i][j] = {0.f, 0.f, 0.f, 0.f};

  STAGE8(0, 0, 0, A, m0); STAGE8(0, 1, 0, A, m0);
  STAGE8(1, 0, 0, B, j0); STAGE8(1, 1, 0, B, j0);
  STAGE8(0, 0, 1, A, m0); STAGE8(0, 1, 1, A, m0);
  STAGE8(1, 0, 1, B, j0);
  asm volatile("s_waitcnt vmcnt(6)" ::: "memory");
  __builtin_amdgcn_s_barrier();

  for (int t = 0; t < 8; ++t) {
    const int buf = t & 1;
    const unsigned short* Ab = &lds[buf * 2 + 0][wm][0];
    const unsigned short* Bb = &lds[buf * 2 + 1][wn >> 1][(wn & 1) * 4096];
    short8 a[8][2], bb[4][2];
#pragma unroll
    for (int rr = 0; rr < 8; ++rr) {
      a[rr][0] = *reinterpret_cast<const short8*>(Ab + rr * 1024 + k0off);
      a[rr][1] = *reinterpret_cast<const short8*>(Ab + rr * 1024 + k1off);
    }
#pragma unroll
    for (int cc = 0; cc < 2; ++cc) {
      bb[cc][0] = *reinterpret_cast<const short8*>(Bb + cc * 1024 + k0off);
      bb[cc][1] = *reinterpret_cast<const short8*>(Bb + cc * 1024 + k1off);
    }
    if (t < 7) STAGE8(1, 1, t + 1, B, j0);
    asm volatile("" ::: "memory");
    __builtin_amdgcn_s_barrier();
    asm volatile("s_waitcnt lgkmcnt(0)" ::: "memory");
    __builtin_amdgcn_sched_barrier(0);
    __builtin_amdgcn_s_setprio(1);
#pragma unroll
    for (int rr = 0; rr < 4; ++rr)
#pragma unroll
      for (int cc = 0; cc < 2; ++cc) {
        acc[rr][cc] = __builtin_amdgcn_mfma_f32_16x16x32_bf16(a[rr][0], bb[cc][0], acc[rr][cc], 0, 0, 0);
        acc[rr][cc] = __builtin_amdgcn_mfma_f32_16x16x32_bf16(a[rr][1], bb[cc][1], acc[rr][cc], 0, 0, 0);
      }
    __builtin_amdgcn_s_setprio(0);
    asm volatile("" ::: "memory");
    __builtin_amdgcn_s_barrier();
#pragma unroll
    for (int cc = 2; cc < 4; ++cc) {
      bb[cc][0] = *reinterpret_cast<const short8*>(Bb + cc * 1024 + k0off);
      bb[cc][1] = *reinterpret_cast<const short8*>(Bb + cc * 1024 + k1off);
    }
    if (t < 6) STAGE8(0, 0, t + 2, A, m0);
    asm volatile("" ::: "memory");
    __builtin_amdgcn_s_barrier();
    asm volatile("s_waitcnt lgkmcnt(0)" ::: "memory");
    __builtin_amdgcn_sched_barrier(0);
    __builtin_amdgcn_s_setprio(1);
#pragma unroll
    for (int rr = 0; rr < 4; ++rr)
#pragma unroll
      for (int cc = 2; cc < 4; ++cc) {
        acc[rr][cc] = __builtin_amdgcn_mfma_f32_16x16x32_bf16(a[rr][0], bb[cc][0], acc[rr][cc], 0, 0, 0);
        acc[rr][cc] = __builtin_amdgcn_mfma_f32_16x16x32_bf16(a[rr][1], bb[cc][1], acc[rr][cc], 0, 0, 0);
      }
    __builtin_amdgcn_s_setprio(0);
    asm volatile("" ::: "memory");
    __builtin_amdgcn_s_barrier();
    if (t < 6) STAGE8(0, 1, t + 2, A, m0);
    asm volatile("" ::: "memory");
    __builtin_amdgcn_s_barrier();
    __builtin_amdgcn_s_setprio(1);
#pragma unroll
    for (int rr = 4; rr < 8; ++rr)
#pragma unroll
      for (int cc = 0; cc < 2; ++cc) {
        acc[rr][cc] = __builtin_amdgcn_mfma_f32_16x16x32_bf16(a[rr][0], bb[cc][0], acc[rr][cc], 0, 0, 0);
        acc[rr][cc] = __builtin_amdgcn_mfma_f32_16x16x32_bf16(a[rr][1], bb[cc][1], acc[rr][cc], 0, 0, 0);
      }
    __builtin_amdgcn_s_setprio(0);
    asm volatile("" ::: "memory");
    __builtin_amdgcn_s_barrier();
    if (t < 6) STAGE8(1, 0, t + 2, B, j0);
    asm volatile("" ::: "memory");
    __builtin_amdgcn_s_barrier();
    __builtin_amdgcn_s_setprio(1);
#pragma unroll
    for (int rr = 4; rr < 8; ++rr)
#pragma unroll
      for (int cc = 2; cc < 4; ++cc) {
        acc[rr][cc] = __builtin_amdgcn_mfma_f32_16x16x32_bf16(a[rr][0], bb[cc][0], acc[rr][cc], 0, 0, 0);
        acc[rr][cc] = __builtin_amdgcn_mfma_f32_16x16x32_bf16(a[rr][1], bb[cc][1], acc[rr][cc], 0, 0, 0);
      }
    __builtin_amdgcn_s_setprio(0);
    asm volatile("" ::: "memory");
    if (t < 6) {
      asm volatile("s_waitcnt vmcnt(6)" ::: "memory");
    } else if (t == 6) {
      asm volatile("s_waitcnt vmcnt(0)" ::: "memory");
    }
    __builtin_amdgcn_s_barrier();
  }

  // epilogue: bias + dp-interleaved pack -> one uint2 store per fragment
#pragma unroll
  for (int rr = 0; rr < 8; ++rr) {
#pragma unroll
    for (int cc = 0; cc < 4; ++cc) {
      const int row = m0 + wm * 128 + rr * 16 + lqq * 4;
      const int col = j0 + wn * 64 + cc * 16 + l16;
      const int t_ = col >> 12, n = col & 4095;
      const int mat = row >> 9;
      const int hh = (row >> 6) & 7;
      const int d = row & 63;
      const int ch = d >> 3;
      const int dp = (d & 7) >> 1;   // 0 or 2
      const size_t base = (size_t)((mat * 8 + hh) * 8 + ch) * 393216;  // 24*4096*4
      uint2 st;
      st.x = pkbf(acc[rr][cc][0] + bias[row], acc[rr][cc][1] + bias[row + 1]);
      st.y = pkbf(acc[rr][cc][2] + bias[row + 2], acc[rr][cc][3] + bias[row + 3]);
      *reinterpret_cast<uint2*>(&outP[base + ((size_t)t_ * 4096 + n) * 4 + dp]) = st;
    }
  }
}

// ---------------- K4: proj GEMM (unchanged) ----------------
__global__ __launch_bounds__(256, 3) void k_proj(
    const unsigned short* __restrict__ A,   // [512][512] bf16
    const unsigned short* __restrict__ B,   // [64][JTOT][8] bf16 (chunked ao)
    const float* __restrict__ bias,         // [512]
    const float* __restrict__ xres,
    float* __restrict__ outf) {
  __shared__ __attribute__((aligned(16))) unsigned short As[2][8192];
  const int bid = blockIdx.x;
  const int cpx = 3072 >> 3;
  const int lid = (bid & 7) * cpx + (bid >> 3);
  const int mt = lid & 3, jt = lid >> 2;
  const int m0 = mt * 128, j0 = jt * 128;
  const int tid = threadIdx.x;
  const int w = tid >> 6, lane = tid & 63;
  const int l16 = lane & 15, lqq = lane >> 4;
  const int wm = w >> 1, wn = w & 1;
  const int srow8 = lane >> 3;
  const int sslot = (lane & 7) ^ srow8;
  const int k0off = l16 * 64 + ((lqq ^ (l16 & 7)) * 8);
  const int k1off = l16 * 64 + (((lqq + 4) ^ (l16 & 7)) * 8);

  f32x4 acc[4][4];
#pragma unroll
  for (int i = 0; i < 4; ++i)
#pragma unroll
    for (int j = 0; j < 4; ++j) acc[i][j] = {0.f, 0.f, 0.f, 0.f};

#define PSTAGE(buf, tile)                                                             \
  {                                                                                   \
    _Pragma("unroll")                                                                 \
    for (int m_ = 0; m_ < 4; ++m_) {                                                  \
      unsigned short* _l = &As[buf][m_ * 2048 + w * 512];                             \
      const unsigned short* _g = A +                                                  \
          (size_t)(m0 + m_ * 32 + w * 8 + srow8) * 512 + (tile) * 64 + sslot * 8;     \
      gload_lds16(_g, _l);                                                            \
    }                                                                                 \
  }

#define LOADB(dst, tt)                                                                \
  {                                                                                   \
    _Pragma("unroll")                                                                 \
    for (int cc = 0; cc < 4; ++cc) {                                                  \
      const int jj_ = j0 + wn * 64 + cc * 16 + l16;                                   \
      _Pragma("unroll")                                                               \
      for (int ks = 0; ks < 2; ++ks)                                                  \
        dst[cc][ks] = *reinterpret_cast<const short8*>(                               \
            &B[((size_t)((tt) * 8 + ks * 4 + lqq) * JTOT + jj_) * 8]);                \
    }                                                                                 \
  }

#define PSTEP(t, CUR, NXT)                                                            \
  {                                                                                   \
    if ((t) < 7) { PSTAGE(((t) + 1) & 1, (t) + 1); LOADB(NXT, (t) + 1); }             \
    const unsigned short* Ab = &As[(t) & 1][(wm * 64) * 64];                          \
    _Pragma("unroll")                                                                 \
    for (int rr = 0; rr < 4; ++rr) {                                                  \
      short8 a0 = *reinterpret_cast<const short8*>(Ab + rr * 1024 + k0off);           \
      short8 a1 = *reinterpret_cast<const short8*>(Ab + rr * 1024 + k1off);           \
      _Pragma("unroll")                                                               \
      for (int cc = 0; cc < 4; ++cc) {                                                \
        acc[rr][cc] = __builtin_amdgcn_mfma_f32_16x16x32_bf16(a0, CUR[cc][0], acc[rr][cc], 0, 0, 0); \
        acc[rr][cc] = __builtin_amdgcn_mfma_f32_16x16x32_bf16(a1, CUR[cc][1], acc[rr][cc], 0, 0, 0); \
      }                                                                               \
    }                                                                                 \
    __syncthreads();                                                                  \
  }

  short8 bbA[4][2], bbB[4][2];
  PSTAGE(0, 0);
  LOADB(bbA, 0);
  __syncthreads();

  PSTEP(0, bbA, bbB);
  PSTEP(1, bbB, bbA);
  PSTEP(2, bbA, bbB);
  PSTEP(3, bbB, bbA);
  PSTEP(4, bbA, bbB);
  PSTEP(5, bbB, bbA);
  PSTEP(6, bbA, bbB);
  PSTEP(7, bbB, bbA);

#pragma unroll
  for (int mi = 0; mi < 4; ++mi) {
#pragma unroll
    for (int ni = 0; ni < 4; ++ni) {
      const int dbase = m0 + wm * 64 + mi * 16 + lqq * 4;
      const int jj = j0 + wn * 64 + ni * 16 + l16;
      const int t_ = jj >> 12, n = jj & 4095;
      const int b_ = n >> 10, hw = n & 1023;
#pragma unroll
      for (int r = 0; r < 4; ++r) {
        size_t o = (((size_t)(b_ * 512 + dbase + r) * 24 + t_) << 10) + hw;
        outf[o] = xres[o] + acc[mi][ni][r] + bias[dbase + r];
      }
    }
  }
}

// ---------------- K3: attention v6 — Q direct-to-reg, K/V LDS ping-pong, 1 barrier/chunk ----------------
// qkvP[mat][h][chunk][t][n][dp] u32. kb[2][1536] uint4 ping-pong (K in QK phase, V in PV).
__global__ __launch_bounds__(512) void k_attn(const uint32_t* __restrict__ qkvP,
                                              unsigned short* __restrict__ aoC) {
  __shared__ uint4 kb[2][1536];   // 48 KiB
  const int ntile = blockIdx.x, h = blockIdx.y;
  const int n0 = ntile * 64;
  const int tid = threadIdx.x;
  const int lane = tid & 63, slot = tid >> 6;
  const int t0 = slot * 3;
  const int BLK = 393216;                 // u32 per (mat,h,chunk) = 24*4096*4
  const size_t bQ = (size_t)((0 * 8 + h) * 8) * BLK;
  const size_t bK = (size_t)((1 * 8 + h) * 8) * BLK;
  const size_t bV = (size_t)((2 * 8 + h) * 8) * BLK;
  const int ub = tid & 448;               // wave-uniform (w*64)

  // unit u in [0,1536): t = u>>6, nn = u&63; global u32 = (t*4096 + n0+nn)*4; LDS uint4 = u.
#define STAGE_M(cbase, dstbuf)                                                        \
  {                                                                                   \
    _Pragma("unroll")                                                                 \
    for (int p = 0; p < 3; ++p) {                                                     \
      const int u = p * 512 + tid;                                                    \
      gload_lds16(qkvP + (cbase) + ((size_t)(u >> 6) * 4096 + n0 + (u & 63)) * 4,     \
                  (void*)(&kb[dstbuf][p * 512 + ub]));                                \
    }                                                                                 \
  }

  float S[3][24];
#pragma unroll
  for (int a = 0; a < 3; ++a)
#pragma unroll
    for (int s = 0; s < 24; ++s) S[a][s] = 0.f;

  // prologue: K chunk 0 -> kb[0]
  STAGE_M(bK, 0);
  asm volatile("s_waitcnt vmcnt(0)" ::: "memory");
  __builtin_amdgcn_s_barrier();

  // ---- QK^T phase: 1 barrier per chunk; stage next K (or V0 at c==7) first
  for (int c = 0; c < 8; ++c) {
    if (c < 7) {
      STAGE_M(bK + (size_t)(c + 1) * BLK, (c + 1) & 1);
    } else {
      STAGE_M(bV, 0);   // V chunk 0 into kb[0]; chunk 7 computes from kb[1]
    }
    // Q for this chunk: direct per-thread loads (lane-coalesced, no LDS)
    uint4 qv[3];
#pragma unroll
    for (int a = 0; a < 3; ++a)
      qv[a] = *reinterpret_cast<const uint4*>(
          qkvP + bQ + (size_t)c * BLK + ((size_t)(t0 + a) * 4096 + n0 + lane) * 4);
#if !HAS_DOT2
    float qf[3][8];
#pragma unroll
    for (int a = 0; a < 3; ++a) {
      qf[a][0] = bflo(qv[a].x); qf[a][1] = bfhi(qv[a].x);
      qf[a][2] = bflo(qv[a].y); qf[a][3] = bfhi(qv[a].y);
      qf[a][4] = bflo(qv[a].z); qf[a][5] = bfhi(qv[a].z);
      qf[a][6] = bflo(qv[a].w); qf[a][7] = bfhi(qv[a].w);
    }
#endif
    const uint4* kbuf = kb[c & 1];
#pragma unroll
    for (int s = 0; s < 24; ++s) {
      const uint4 kk = kbuf[s * 64 + lane];
#if HAS_DOT2
#pragma unroll
      for (int a = 0; a < 3; ++a) {
        S[a][s] = __builtin_amdgcn_fdot2_f32_bf16(asbf2(qv[a].x), asbf2(kk.x), S[a][s], false);
        S[a][s] = __builtin_amdgcn_fdot2_f32_bf16(asbf2(qv[a].y), asbf2(kk.y), S[a][s], false);
        S[a][s] = __builtin_amdgcn_fdot2_f32_bf16(asbf2(qv[a].z), asbf2(kk.z), S[a][s], false);
        S[a][s] = __builtin_amdgcn_fdot2_f32_bf16(asbf2(qv[a].w), asbf2(kk.w), S[a][s], false);
      }
#else
      const float k0 = bflo(kk.x), k1 = bfhi(kk.x), k2 = bflo(kk.y), k3 = bfhi(kk.y);
      const float k4 = bflo(kk.z), k5 = bfhi(kk.z), k6 = bflo(kk.w), k7 = bfhi(kk.w);
#pragma unroll
      for (int a = 0; a < 3; ++a) {
        S[a][s] = fmaf(qf[a][0], k0, S[a][s]); S[a][s] = fmaf(qf[a][1], k1, S[a][s]);
        S[a][s] = fmaf(qf[a][2], k2, S[a][s]); S[a][s] = fmaf(qf[a][3], k3, S[a][s]);
        S[a][s] = fmaf(qf[a][4], k4, S[a][s]); S[a][s] = fmaf(qf[a][5], k5, S[a][s]);
        S[a][s] = fmaf(qf[a][6], k6, S[a][s]); S[a][s] = fmaf(qf[a][7], k7, S[a][s]);
      }
#endif
    }
    asm volatile("s_waitcnt vmcnt(0)" ::: "memory");
    __builtin_amdgcn_s_barrier();
  }

  // ---- softmax (scale 1/sqrt(64) = 0.125); V chunk 0 already resident in kb[0]
#pragma unroll
  for (int a = 0; a < 3; ++a) {
    float mx = S[a][0];
#pragma unroll
    for (int s = 1; s < 24; ++s) mx = fmaxf(mx, S[a][s]);
    float sum = 0.f;
#pragma unroll
    for (int s = 0; s < 24; ++s) {
      float e = __expf((S[a][s] - mx) * 0.125f);
      S[a][s] = e; sum += e;
    }
    float inv = 1.f / sum;
#pragma unroll
    for (int s = 0; s < 24; ++s) S[a][s] *= inv;
  }

  // ---- PV phase: same ping-pong, 1 barrier per chunk
  for (int c = 0; c < 8; ++c) {
    if (c < 7) STAGE_M(bV + (size_t)(c + 1) * BLK, (c + 1) & 1);
    f32x2 o2[3][4];
#pragma unroll
    for (int a = 0; a < 3; ++a)
#pragma unroll
      for (int dp = 0; dp < 4; ++dp) o2[a][dp] = {0.f, 0.f};
    const uint4* vbuf = kb[c & 1];
#pragma unroll
    for (int s = 0; s < 24; ++s) {
      const uint4 vv = vbuf[s * 64 + lane];
      f32x2 v0, v1, v2, v3;
      v0.x = bflo(vv.x); v0.y = bfhi(vv.x);
      v1.x = bflo(vv.y); v1.y = bfhi(vv.y);
      v2.x = bflo(vv.z); v2.y = bfhi(vv.z);
      v3.x = bflo(vv.w); v3.y = bfhi(vv.w);
#pragma unroll
      for (int a = 0; a < 3; ++a) {
        o2[a][0] += S[a][s] * v0;
        o2[a][1] += S[a][s] * v1;
        o2[a][2] += S[a][s] * v2;
        o2[a][3] += S[a][s] * v3;
      }
    }
#pragma unroll
    for (int a = 0; a < 3; ++a) {
      uint4 wv;
      wv.x = pkbf(o2[a][0].x, o2[a][0].y);
      wv.y = pkbf(o2[a][1].x, o2[a][1].y);
      wv.z = pkbf(o2[a][2].x, o2[a][2].y);
      wv.w = pkbf(o2[a][3].x, o2[a][3].y);
      const size_t unit = (size_t)(h * 8 + c) * JTOT + (size_t)(t0 + a) * NN + n0 + lane;
      *reinterpret_cast<uint4*>(&aoC[unit * 8]) = wv;
    }
    asm volatile("s_waitcnt vmcnt(0)" ::: "memory");
    __builtin_amdgcn_s_barrier();
  }
}

extern "C" void kernel_launch(void* const* d_in, const int* in_sizes, int n_in,
                              void* d_out, int out_size, void* d_ws, size_t ws_size,
                              hipStream_t stream) {
  (void)in_sizes; (void)n_in; (void)out_size; (void)ws_size;
  const float* x     = (const float*)d_in[0];
  const float* gnw   = (const float*)d_in[1];
  const float* gnb   = (const float*)d_in[2];
  const float* qkvw  = (const float*)d_in[3];
  const float* qkvb  = (const float*)d_in[4];
  const float* projw = (const float*)d_in[5];
  const float* projb = (const float*)d_in[6];
  float* out = (float*)d_out;
  char* ws = (char*)d_ws;

  unsigned short* qkvw_bf = (unsigned short*)(ws);                    // 1,572,864 B
  unsigned short* projw_bf = (unsigned short*)(ws + 1572864);         //   524,288 B
  float* mean = (float*)(ws + 2097152);                               //   524,288 B
  float* rstd = (float*)(ws + 2621440);                               //   524,288 B
  unsigned short* xn  = (unsigned short*)(ws + 3145728);              // 100,663,296 B (also attnout chunked)
  uint32_t* qkvP = (uint32_t*)(ws + 3145728 + 100663296);             // 301,989,888 B (packed, dp-interleaved)

  k_cvt<<<dim3(3072), dim3(256), 0, stream>>>(qkvw, projw, qkvw_bf, projw_bf);
  k_stats<<<dim3(2048), dim3(256), 0, stream>>>(x, mean, rstd);
  k_norm<<<dim3(3072), dim3(256), 0, stream>>>(x, mean, rstd, gnw, gnb, xn);
  k_gemm8<<<dim3(2304), dim3(512), 0, stream>>>(qkvw_bf, xn, qkvb, qkvP);
  k_attn<<<dim3(64, 8), dim3(512), 0, stream>>>(qkvP, xn);  // chunked attnout overwrites xn
  k_proj<<<dim3(3072), dim3(256), 0, stream>>>(projw_bf, xn, projb, x, out);
}

// Round 18
// 512.928 us; speedup vs baseline: 1.0087x; 1.0087x over previous
//
#include <hip/hip_runtime.h>
#include <hip/hip_bf16.h>
#include <stdint.h>

#define C_    512
#define T_    24
#define HWSZ  1024
#define NN    4096
#define JTOT  98304   // T_*NN
#define EPSV  1e-5f

typedef short short8 __attribute__((ext_vector_type(8)));
typedef short short4v __attribute__((ext_vector_type(4)));
typedef float f32x4 __attribute__((ext_vector_type(4)));
typedef float f32x2 __attribute__((ext_vector_type(2)));
typedef __bf16 bf16x2 __attribute__((ext_vector_type(2)));

typedef __attribute__((address_space(1))) const uint32_t glob_u32;
typedef __attribute__((address_space(3))) uint32_t lds_u32;

#if __has_builtin(__builtin_amdgcn_fdot2_f32_bf16)
#define HAS_DOT2 1
#else
#define HAS_DOT2 0
#endif

__device__ __forceinline__ unsigned short f2bf(float f) {
  union { float f; unsigned u; } v; v.f = f;
  unsigned r = v.u + 0x7fffu + ((v.u >> 16) & 1u);
  return (unsigned short)(r >> 16);
}
__device__ __forceinline__ float bf2f(unsigned short b) {
  union { unsigned u; float f; } v; v.u = ((unsigned)b) << 16;
  return v.f;
}
__device__ __forceinline__ float bflo(uint32_t u) {
  union { unsigned u; float f; } v; v.u = u << 16; return v.f;
}
__device__ __forceinline__ float bfhi(uint32_t u) {
  union { unsigned u; float f; } v; v.u = u & 0xffff0000u; return v.f;
}
__device__ __forceinline__ uint32_t pkbf(float a, float b) {
  return (uint32_t)f2bf(a) | ((uint32_t)f2bf(b) << 16);
}
__device__ __forceinline__ bf16x2 asbf2(uint32_t u) {
  union { uint32_t u; bf16x2 v; } c; c.u = u; return c.v;
}

__device__ __forceinline__ void gload_lds16(const void* g, void* l) {
  __builtin_amdgcn_global_load_lds((glob_u32*)g, (lds_u32*)l, 16, 0, 0);
}

// ---------------- K0: weight f32 -> bf16 ----------------
__global__ void k_cvt(const float* __restrict__ qkvw, const float* __restrict__ projw,
                      unsigned short* __restrict__ qkvw_bf, unsigned short* __restrict__ projw_bf) {
  int i = blockIdx.x * 256 + threadIdx.x;
  if (i < 786432) qkvw_bf[i] = f2bf(qkvw[i]);
  if (i < 262144) projw_bf[i] = f2bf(projw[i]);
}

// ---------------- K1a: GroupNorm stats ----------------
__global__ __launch_bounds__(256) void k_stats(const float* __restrict__ x,
                                               float* __restrict__ mean, float* __restrict__ rstd) {
  int bid = blockIdx.x;
  int g = bid & 31, hwt = (bid >> 5) & 15, b = bid >> 9;
  int tid = threadIdx.x, lane = tid & 63, grp = tid >> 6;
  int hw = hwt * 64 + lane;
  float s = 0.f, sq = 0.f;
  for (int ct = grp; ct < 384; ct += 4) {
    int c = g * 16 + ct / 24;
    int t = ct % 24;
    float v = x[((size_t)((b * 512 + c) * 24 + t) << 10) + hw];
    s += v; sq += v * v;
  }
  __shared__ float ls[4][64], lq[4][64];
  ls[grp][lane] = s; lq[grp][lane] = sq;
  __syncthreads();
  if (tid < 64) {
    float S = ls[0][tid] + ls[1][tid] + ls[2][tid] + ls[3][tid];
    float Q = lq[0][tid] + lq[1][tid] + lq[2][tid] + lq[3][tid];
    float m = S * (1.f / 384.f);
    float var = Q * (1.f / 384.f) - m * m;
    int n = b * HWSZ + hwt * 64 + tid;
    mean[n * 32 + g] = m;
    rstd[n * 32 + g] = rsqrtf(var + EPSV);
  }
}

// ---------------- K1b: normalize + transpose to Xn[j][c] bf16 (v3) ----------------
__global__ __launch_bounds__(256) void k_norm(const float* __restrict__ x,
                                              const float* __restrict__ mean, const float* __restrict__ rstd,
                                              const float* __restrict__ gnw, const float* __restrict__ gnb,
                                              unsigned short* __restrict__ xn) {
  __shared__ unsigned short xs[64][260];
  const int bid = blockIdx.x;
  const int hwt = bid & 15;
  const int chalf = (bid >> 4) & 1;
  const int tb = bid >> 5;
  const int t = tb % 24, b = tb / 24;
  const int hw0 = hwt * 64;
  const int tid = threadIdx.x;
  const int w = tid >> 6, lane = tid & 63;

  const int cslot = w * 4 + (lane >> 4);
  const int hwr = (lane & 15) * 4;
#pragma unroll
  for (int k = 0; k < 8; ++k) {
    const int crel = k * 32 + cslot * 2;
    const int c = chalf * 256 + crel;
    const float4 v0 = *reinterpret_cast<const float4*>(
        &x[(((size_t)(b * 512 + c) * 24 + t) << 10) + hw0 + hwr]);
    const float4 v1 = *reinterpret_cast<const float4*>(
        &x[(((size_t)(b * 512 + c + 1) * 24 + t) << 10) + hw0 + hwr]);
    *reinterpret_cast<uint32_t*>(&xs[hwr + 0][crel]) = pkbf(v0.x, v1.x);
    *reinterpret_cast<uint32_t*>(&xs[hwr + 1][crel]) = pkbf(v0.y, v1.y);
    *reinterpret_cast<uint32_t*>(&xs[hwr + 2][crel]) = pkbf(v0.z, v1.z);
    *reinterpret_cast<uint32_t*>(&xs[hwr + 3][crel]) = pkbf(v0.w, v1.w);
  }

  const int crel8 = (lane & 31) * 8;
  const int c8 = chalf * 256 + crel8;
  const int g = c8 >> 4;
  float gw[8], gb[8];
#pragma unroll
  for (int i = 0; i < 8; ++i) { gw[i] = gnw[c8 + i]; gb[i] = gnb[c8 + i]; }
  float mm[8], rr[8];
#pragma unroll
  for (int p = 0; p < 8; ++p) {
    const int nrel = (p * 4 + w) * 2 + (lane >> 5);
    const int ng = b * HWSZ + hw0 + nrel;
    mm[p] = mean[ng * 32 + g];
    rr[p] = rstd[ng * 32 + g];
  }
  __syncthreads();

#pragma unroll
  for (int p = 0; p < 8; ++p) {
    const int nrel = (p * 4 + w) * 2 + (lane >> 5);
    const short4v lo = *reinterpret_cast<const short4v*>(&xs[nrel][crel8]);
    const short4v hi = *reinterpret_cast<const short4v*>(&xs[nrel][crel8 + 4]);
    float y[8];
#pragma unroll
    for (int i = 0; i < 4; ++i) {
      y[i]     = (bf2f((unsigned short)lo[i]) - mm[p]) * rr[p] * gw[i]     + gb[i];
      y[i + 4] = (bf2f((unsigned short)hi[i]) - mm[p]) * rr[p] * gw[i + 4] + gb[i + 4];
    }
    uint4 wv;
    wv.x = pkbf(y[0], y[1]);
    wv.y = pkbf(y[2], y[3]);
    wv.z = pkbf(y[4], y[5]);
    wv.w = pkbf(y[6], y[7]);
    const size_t j = (size_t)t * NN + b * HWSZ + hw0 + nrel;
    *reinterpret_cast<uint4*>(&xn[j * C_ + c8]) = wv;
  }
}

// ---------------- K2: 256x256 8-phase bf16 MFMA GEMM (QKV; dp-interleaved packed out) ----------------
// Output: qkvP[mat 3][h 8][chunk 8][t 24][n 4096][dp 4] u32 (bf16 pair per u32).
#define STAGE8(mat, half, tile, Gptr, row0)                                           \
  {                                                                                   \
    unsigned short* _l = &lds[(((tile) & 1) * 2 + (mat))][half][(w * 2) * 512];       \
    const unsigned short* _g = (Gptr) +                                               \
        (size_t)((row0) + (half) * 128 + (w * 2) * 8 + srow) * 512 +                  \
        (tile) * 64 + sslot * 8;                                                      \
    gload_lds16(_g, _l);                                                              \
    gload_lds16(_g + 8 * 512, _l + 512);                                              \
  }

__global__ __launch_bounds__(512, 2) void k_gemm8(
    const unsigned short* __restrict__ A,   // [1536][512] bf16
    const unsigned short* __restrict__ B,   // [JTOT][512] bf16
    const float* __restrict__ bias,         // [1536]
    uint32_t* __restrict__ outP) {          // packed qkvP
  __shared__ __attribute__((aligned(16))) unsigned short lds[4][2][8192];
  const int bid = blockIdx.x;
  const int cpx = 2304 >> 3;
  const int lid = (bid & 7) * cpx + (bid >> 3);
  const int mt = lid % 6, jt = lid / 6;
  const int m0 = mt * 256, j0 = jt * 256;
  const int tid = threadIdx.x;
  const int w = tid >> 6, lane = tid & 63;
  const int l16 = lane & 15, lqq = lane >> 4;
  const int wm = w >> 2, wn = w & 3;
  const int srow = lane >> 3;
  const int sslot = (lane & 7) ^ srow;
  const int k0off = l16 * 64 + ((lqq ^ (l16 & 7)) * 8);
  const int k1off = l16 * 64 + (((lqq + 4) ^ (l16 & 7)) * 8);

  f32x4 acc[8][4];
#pragma unroll
  for (int i = 0; i < 8; ++i)
#pragma unroll
    for (int j = 0; j < 4; ++j) acc[i][j] = {0.f, 0.f, 0.f, 0.f};

  STAGE8(0, 0, 0, A, m0); STAGE8(0, 1, 0, A, m0);
  STAGE8(1, 0, 0, B, j0); STAGE8(1, 1, 0, B, j0);
  STAGE8(0, 0, 1, A, m0); STAGE8(0, 1, 1, A, m0);
  STAGE8(1, 0, 1, B, j0);
  asm volatile("s_waitcnt vmcnt(6)" ::: "memory");
  __builtin_amdgcn_s_barrier();

  for (int t = 0; t < 8; ++t) {
    const int buf = t & 1;
    const unsigned short* Ab = &lds[buf * 2 + 0][wm][0];
    const unsigned short* Bb = &lds[buf * 2 + 1][wn >> 1][(wn & 1) * 4096];
    short8 a[8][2], bb[4][2];
#pragma unroll
    for (int rr = 0; rr < 8; ++rr) {
      a[rr][0] = *reinterpret_cast<const short8*>(Ab + rr * 1024 + k0off);
      a[rr][1] = *reinterpret_cast<const short8*>(Ab + rr * 1024 + k1off);
    }
#pragma unroll
    for (int cc = 0; cc < 2; ++cc) {
      bb[cc][0] = *reinterpret_cast<const short8*>(Bb + cc * 1024 + k0off);
      bb[cc][1] = *reinterpret_cast<const short8*>(Bb + cc * 1024 + k1off);
    }
    if (t < 7) STAGE8(1, 1, t + 1, B, j0);
    asm volatile("" ::: "memory");
    __builtin_amdgcn_s_barrier();
    asm volatile("s_waitcnt lgkmcnt(0)" ::: "memory");
    __builtin_amdgcn_sched_barrier(0);
    __builtin_amdgcn_s_setprio(1);
#pragma unroll
    for (int rr = 0; rr < 4; ++rr)
#pragma unroll
      for (int cc = 0; cc < 2; ++cc) {
        acc[rr][cc] = __builtin_amdgcn_mfma_f32_16x16x32_bf16(a[rr][0], bb[cc][0], acc[rr][cc], 0, 0, 0);
        acc[rr][cc] = __builtin_amdgcn_mfma_f32_16x16x32_bf16(a[rr][1], bb[cc][1], acc[rr][cc], 0, 0, 0);
      }
    __builtin_amdgcn_s_setprio(0);
    asm volatile("" ::: "memory");
    __builtin_amdgcn_s_barrier();
#pragma unroll
    for (int cc = 2; cc < 4; ++cc) {
      bb[cc][0] = *reinterpret_cast<const short8*>(Bb + cc * 1024 + k0off);
      bb[cc][1] = *reinterpret_cast<const short8*>(Bb + cc * 1024 + k1off);
    }
    if (t < 6) STAGE8(0, 0, t + 2, A, m0);
    asm volatile("" ::: "memory");
    __builtin_amdgcn_s_barrier();
    asm volatile("s_waitcnt lgkmcnt(0)" ::: "memory");
    __builtin_amdgcn_sched_barrier(0);
    __builtin_amdgcn_s_setprio(1);
#pragma unroll
    for (int rr = 0; rr < 4; ++rr)
#pragma unroll
      for (int cc = 2; cc < 4; ++cc) {
        acc[rr][cc] = __builtin_amdgcn_mfma_f32_16x16x32_bf16(a[rr][0], bb[cc][0], acc[rr][cc], 0, 0, 0);
        acc[rr][cc] = __builtin_amdgcn_mfma_f32_16x16x32_bf16(a[rr][1], bb[cc][1], acc[rr][cc], 0, 0, 0);
      }
    __builtin_amdgcn_s_setprio(0);
    asm volatile("" ::: "memory");
    __builtin_amdgcn_s_barrier();
    if (t < 6) STAGE8(0, 1, t + 2, A, m0);
    asm volatile("" ::: "memory");
    __builtin_amdgcn_s_barrier();
    __builtin_amdgcn_s_setprio(1);
#pragma unroll
    for (int rr = 4; rr < 8; ++rr)
#pragma unroll
      for (int cc = 0; cc < 2; ++cc) {
        acc[rr][cc] = __builtin_amdgcn_mfma_f32_16x16x32_bf16(a[rr][0], bb[cc][0], acc[rr][cc], 0, 0, 0);
        acc[rr][cc] = __builtin_amdgcn_mfma_f32_16x16x32_bf16(a[rr][1], bb[cc][1], acc[rr][cc], 0, 0, 0);
      }
    __builtin_amdgcn_s_setprio(0);
    asm volatile("" ::: "memory");
    __builtin_amdgcn_s_barrier();
    if (t < 6) STAGE8(1, 0, t + 2, B, j0);
    asm volatile("" ::: "memory");
    __builtin_amdgcn_s_barrier();
    __builtin_amdgcn_s_setprio(1);
#pragma unroll
    for (int rr = 4; rr < 8; ++rr)
#pragma unroll
      for (int cc = 2; cc < 4; ++cc) {
        acc[rr][cc] = __builtin_amdgcn_mfma_f32_16x16x32_bf16(a[rr][0], bb[cc][0], acc[rr][cc], 0, 0, 0);
        acc[rr][cc] = __builtin_amdgcn_mfma_f32_16x16x32_bf16(a[rr][1], bb[cc][1], acc[rr][cc], 0, 0, 0);
      }
    __builtin_amdgcn_s_setprio(0);
    asm volatile("" ::: "memory");
    if (t < 6) {
      asm volatile("s_waitcnt vmcnt(6)" ::: "memory");
    } else if (t == 6) {
      asm volatile("s_waitcnt vmcnt(0)" ::: "memory");
    }
    __builtin_amdgcn_s_barrier();
  }

  // epilogue: bias + dp-interleaved pack -> one uint2 store per fragment
#pragma unroll
  for (int rr = 0; rr < 8; ++rr) {
#pragma unroll
    for (int cc = 0; cc < 4; ++cc) {
      const int row = m0 + wm * 128 + rr * 16 + lqq * 4;
      const int col = j0 + wn * 64 + cc * 16 + l16;
      const int t_ = col >> 12, n = col & 4095;
      const int mat = row >> 9;
      const int hh = (row >> 6) & 7;
      const int d = row & 63;
      const int ch = d >> 3;
      const int dp = (d & 7) >> 1;   // 0 or 2
      const size_t base = (size_t)((mat * 8 + hh) * 8 + ch) * 393216;  // 24*4096*4
      uint2 st;
      st.x = pkbf(acc[rr][cc][0] + bias[row], acc[rr][cc][1] + bias[row + 1]);
      st.y = pkbf(acc[rr][cc][2] + bias[row + 2], acc[rr][cc][3] + bias[row + 3]);
      *reinterpret_cast<uint2*>(&outP[base + ((size_t)t_ * 4096 + n) * 4 + dp]) = st;
    }
  }
}

// ---------------- K4: proj GEMM (unchanged) ----------------
__global__ __launch_bounds__(256, 3) void k_proj(
    const unsigned short* __restrict__ A,   // [512][512] bf16
    const unsigned short* __restrict__ B,   // [64][JTOT][8] bf16 (chunked ao)
    const float* __restrict__ bias,         // [512]
    const float* __restrict__ xres,
    float* __restrict__ outf) {
  __shared__ __attribute__((aligned(16))) unsigned short As[2][8192];
  const int bid = blockIdx.x;
  const int cpx = 3072 >> 3;
  const int lid = (bid & 7) * cpx + (bid >> 3);
  const int mt = lid & 3, jt = lid >> 2;
  const int m0 = mt * 128, j0 = jt * 128;
  const int tid = threadIdx.x;
  const int w = tid >> 6, lane = tid & 63;
  const int l16 = lane & 15, lqq = lane >> 4;
  const int wm = w >> 1, wn = w & 1;
  const int srow8 = lane >> 3;
  const int sslot = (lane & 7) ^ srow8;
  const int k0off = l16 * 64 + ((lqq ^ (l16 & 7)) * 8);
  const int k1off = l16 * 64 + (((lqq + 4) ^ (l16 & 7)) * 8);

  f32x4 acc[4][4];
#pragma unroll
  for (int i = 0; i < 4; ++i)
#pragma unroll
    for (int j = 0; j < 4; ++j) acc[i][j] = {0.f, 0.f, 0.f, 0.f};

#define PSTAGE(buf, tile)                                                             \
  {                                                                                   \
    _Pragma("unroll")                                                                 \
    for (int m_ = 0; m_ < 4; ++m_) {                                                  \
      unsigned short* _l = &As[buf][m_ * 2048 + w * 512];                             \
      const unsigned short* _g = A +                                                  \
          (size_t)(m0 + m_ * 32 + w * 8 + srow8) * 512 + (tile) * 64 + sslot * 8;     \
      gload_lds16(_g, _l);                                                            \
    }                                                                                 \
  }

#define LOADB(dst, tt)                                                                \
  {                                                                                   \
    _Pragma("unroll")                                                                 \
    for (int cc = 0; cc < 4; ++cc) {                                                  \
      const int jj_ = j0 + wn * 64 + cc * 16 + l16;                                   \
      _Pragma("unroll")                                                               \
      for (int ks = 0; ks < 2; ++ks)                                                  \
        dst[cc][ks] = *reinterpret_cast<const short8*>(                               \
            &B[((size_t)((tt) * 8 + ks * 4 + lqq) * JTOT + jj_) * 8]);                \
    }                                                                                 \
  }

#define PSTEP(t, CUR, NXT)                                                            \
  {                                                                                   \
    if ((t) < 7) { PSTAGE(((t) + 1) & 1, (t) + 1); LOADB(NXT, (t) + 1); }             \
    const unsigned short* Ab = &As[(t) & 1][(wm * 64) * 64];                          \
    _Pragma("unroll")                                                                 \
    for (int rr = 0; rr < 4; ++rr) {                                                  \
      short8 a0 = *reinterpret_cast<const short8*>(Ab + rr * 1024 + k0off);           \
      short8 a1 = *reinterpret_cast<const short8*>(Ab + rr * 1024 + k1off);           \
      _Pragma("unroll")                                                               \
      for (int cc = 0; cc < 4; ++cc) {                                                \
        acc[rr][cc] = __builtin_amdgcn_mfma_f32_16x16x32_bf16(a0, CUR[cc][0], acc[rr][cc], 0, 0, 0); \
        acc[rr][cc] = __builtin_amdgcn_mfma_f32_16x16x32_bf16(a1, CUR[cc][1], acc[rr][cc], 0, 0, 0); \
      }                                                                               \
    }                                                                                 \
    __syncthreads();                                                                  \
  }

  short8 bbA[4][2], bbB[4][2];
  PSTAGE(0, 0);
  LOADB(bbA, 0);
  __syncthreads();

  PSTEP(0, bbA, bbB);
  PSTEP(1, bbB, bbA);
  PSTEP(2, bbA, bbB);
  PSTEP(3, bbB, bbA);
  PSTEP(4, bbA, bbB);
  PSTEP(5, bbB, bbA);
  PSTEP(6, bbA, bbB);
  PSTEP(7, bbB, bbA);

#pragma unroll
  for (int mi = 0; mi < 4; ++mi) {
#pragma unroll
    for (int ni = 0; ni < 4; ++ni) {
      const int dbase = m0 + wm * 64 + mi * 16 + lqq * 4;
      const int jj = j0 + wn * 64 + ni * 16 + l16;
      const int t_ = jj >> 12, n = jj & 4095;
      const int b_ = n >> 10, hw = n & 1023;
#pragma unroll
      for (int r = 0; r < 4; ++r) {
        size_t o = (((size_t)(b_ * 512 + dbase + r) * 24 + t_) << 10) + hw;
        outf[o] = xres[o] + acc[mi][ni][r] + bias[dbase + r];
      }
    }
  }
}

// ---------------- K3: attention v5 (verified R16) — b128 LDS reads, dp-interleaved ----------------
// qkvP[mat][h][chunk][t][n][dp] u32. kq[buf][t*64+nn] uint4; buf0 = K/V, buf1 = Q.
__global__ __launch_bounds__(512) void k_attn(const uint32_t* __restrict__ qkvP,
                                              unsigned short* __restrict__ aoC) {
  __shared__ uint4 kq[2][1536];   // 48 KiB
  const int ntile = blockIdx.x, h = blockIdx.y;
  const int n0 = ntile * 64;
  const int tid = threadIdx.x;
  const int lane = tid & 63, slot = tid >> 6;
  const int t0 = slot * 3;
  const int BLK = 393216;                 // u32 per (mat,h,chunk) = 24*4096*4
  const size_t bQ = (size_t)((0 * 8 + h) * 8) * BLK;
  const size_t bK = (size_t)((1 * 8 + h) * 8) * BLK;
  const size_t bV = (size_t)((2 * 8 + h) * 8) * BLK;
  const int ub = tid & 448;               // wave-uniform (w*64)

  // unit u in [0,1536): t = u>>6, nn = u&63; global u32 = (t*4096 + n0+nn)*4; LDS uint4 = u.
#define STAGE_M(cbase, dstbuf)                                                        \
  {                                                                                   \
    _Pragma("unroll")                                                                 \
    for (int p = 0; p < 3; ++p) {                                                     \
      const int u = p * 512 + tid;                                                    \
      gload_lds16(qkvP + (cbase) + ((size_t)(u >> 6) * 4096 + n0 + (u & 63)) * 4,     \
                  (void*)(&kq[dstbuf][p * 512 + ub]));                                \
    }                                                                                 \
  }

#define STAGE_QK(c_)                                                                  \
  {                                                                                   \
    STAGE_M(bK + (size_t)(c_) * BLK, 0);                                              \
    STAGE_M(bQ + (size_t)(c_) * BLK, 1);                                              \
  }

#define STAGE_V(c_) { STAGE_M(bV + (size_t)(c_) * BLK, 0); }

  float S[3][24];
#pragma unroll
  for (int a = 0; a < 3; ++a)
#pragma unroll
    for (int s = 0; s < 24; ++s) S[a][s] = 0.f;

  // ---- QK^T phase
  STAGE_QK(0);
  __syncthreads();
  for (int c = 0; c < 8; ++c) {
    uint4 qv[3];
#pragma unroll
    for (int a = 0; a < 3; ++a) qv[a] = kq[1][(t0 + a) * 64 + lane];
#if !HAS_DOT2
    float qf[3][8];
#pragma unroll
    for (int a = 0; a < 3; ++a) {
      qf[a][0] = bflo(qv[a].x); qf[a][1] = bfhi(qv[a].x);
      qf[a][2] = bflo(qv[a].y); qf[a][3] = bfhi(qv[a].y);
      qf[a][4] = bflo(qv[a].z); qf[a][5] = bfhi(qv[a].z);
      qf[a][6] = bflo(qv[a].w); qf[a][7] = bfhi(qv[a].w);
    }
#endif
#pragma unroll
    for (int s = 0; s < 24; ++s) {
      const uint4 kk = kq[0][s * 64 + lane];
#if HAS_DOT2
#pragma unroll
      for (int a = 0; a < 3; ++a) {
        S[a][s] = __builtin_amdgcn_fdot2_f32_bf16(asbf2(qv[a].x), asbf2(kk.x), S[a][s], false);
        S[a][s] = __builtin_amdgcn_fdot2_f32_bf16(asbf2(qv[a].y), asbf2(kk.y), S[a][s], false);
        S[a][s] = __builtin_amdgcn_fdot2_f32_bf16(asbf2(qv[a].z), asbf2(kk.z), S[a][s], false);
        S[a][s] = __builtin_amdgcn_fdot2_f32_bf16(asbf2(qv[a].w), asbf2(kk.w), S[a][s], false);
      }
#else
      const float k0 = bflo(kk.x), k1 = bfhi(kk.x), k2 = bflo(kk.y), k3 = bfhi(kk.y);
      const float k4 = bflo(kk.z), k5 = bfhi(kk.z), k6 = bflo(kk.w), k7 = bfhi(kk.w);
#pragma unroll
      for (int a = 0; a < 3; ++a) {
        S[a][s] = fmaf(qf[a][0], k0, S[a][s]); S[a][s] = fmaf(qf[a][1], k1, S[a][s]);
        S[a][s] = fmaf(qf[a][2], k2, S[a][s]); S[a][s] = fmaf(qf[a][3], k3, S[a][s]);
        S[a][s] = fmaf(qf[a][4], k4, S[a][s]); S[a][s] = fmaf(qf[a][5], k5, S[a][s]);
        S[a][s] = fmaf(qf[a][6], k6, S[a][s]); S[a][s] = fmaf(qf[a][7], k7, S[a][s]);
      }
#endif
    }
    __syncthreads();
    if (c < 7) {
      STAGE_QK(c + 1);
      __syncthreads();
    }
  }

  // ---- softmax (scale 1/sqrt(64) = 0.125)
#pragma unroll
  for (int a = 0; a < 3; ++a) {
    float mx = S[a][0];
#pragma unroll
    for (int s = 1; s < 24; ++s) mx = fmaxf(mx, S[a][s]);
    float sum = 0.f;
#pragma unroll
    for (int s = 0; s < 24; ++s) {
      float e = __expf((S[a][s] - mx) * 0.125f);
      S[a][s] = e; sum += e;
    }
    float inv = 1.f / sum;
#pragma unroll
    for (int s = 0; s < 24; ++s) S[a][s] *= inv;
  }

  // ---- PV phase
  STAGE_V(0);
  __syncthreads();
  for (int c = 0; c < 8; ++c) {
    f32x2 o2[3][4];
#pragma unroll
    for (int a = 0; a < 3; ++a)
#pragma unroll
      for (int dp = 0; dp < 4; ++dp) o2[a][dp] = {0.f, 0.f};
#pragma unroll
    for (int s = 0; s < 24; ++s) {
      const uint4 vv = kq[0][s * 64 + lane];
      f32x2 v0, v1, v2, v3;
      v0.x = bflo(vv.x); v0.y = bfhi(vv.x);
      v1.x = bflo(vv.y); v1.y = bfhi(vv.y);
      v2.x = bflo(vv.z); v2.y = bfhi(vv.z);
      v3.x = bflo(vv.w); v3.y = bfhi(vv.w);
#pragma unroll
      for (int a = 0; a < 3; ++a) {
        o2[a][0] += S[a][s] * v0;
        o2[a][1] += S[a][s] * v1;
        o2[a][2] += S[a][s] * v2;
        o2[a][3] += S[a][s] * v3;
      }
    }
#pragma unroll
    for (int a = 0; a < 3; ++a) {
      uint4 wv;
      wv.x = pkbf(o2[a][0].x, o2[a][0].y);
      wv.y = pkbf(o2[a][1].x, o2[a][1].y);
      wv.z = pkbf(o2[a][2].x, o2[a][2].y);
      wv.w = pkbf(o2[a][3].x, o2[a][3].y);
      const size_t unit = (size_t)(h * 8 + c) * JTOT + (size_t)(t0 + a) * NN + n0 + lane;
      *reinterpret_cast<uint4*>(&aoC[unit * 8]) = wv;
    }
    __syncthreads();
    if (c < 7) {
      STAGE_V(c + 1);
      __syncthreads();
    }
  }
}

extern "C" void kernel_launch(void* const* d_in, const int* in_sizes, int n_in,
                              void* d_out, int out_size, void* d_ws, size_t ws_size,
                              hipStream_t stream) {
  (void)in_sizes; (void)n_in; (void)out_size; (void)ws_size;
  const float* x     = (const float*)d_in[0];
  const float* gnw   = (const float*)d_in[1];
  const float* gnb   = (const float*)d_in[2];
  const float* qkvw  = (const float*)d_in[3];
  const float* qkvb  = (const float*)d_in[4];
  const float* projw = (const float*)d_in[5];
  const float* projb = (const float*)d_in[6];
  float* out = (float*)d_out;
  char* ws = (char*)d_ws;

  unsigned short* qkvw_bf = (unsigned short*)(ws);                    // 1,572,864 B
  unsigned short* projw_bf = (unsigned short*)(ws + 1572864);         //   524,288 B
  float* mean = (float*)(ws + 2097152);                               //   524,288 B
  float* rstd = (float*)(ws + 2621440);                               //   524,288 B
  unsigned short* xn  = (unsigned short*)(ws + 3145728);              // 100,663,296 B (also attnout chunked)
  uint32_t* qkvP = (uint32_t*)(ws + 3145728 + 100663296);             // 301,989,888 B (packed, dp-interleaved)

  k_cvt<<<dim3(3072), dim3(256), 0, stream>>>(qkvw, projw, qkvw_bf, projw_bf);
  k_stats<<<dim3(2048), dim3(256), 0, stream>>>(x, mean, rstd);
  k_norm<<<dim3(3072), dim3(256), 0, stream>>>(x, mean, rstd, gnw, gnb, xn);
  k_gemm8<<<dim3(2304), dim3(512), 0, stream>>>(qkvw_bf, xn, qkvb, qkvP);
  k_attn<<<dim3(64, 8), dim3(512), 0, stream>>>(qkvP, xn);  // chunked attnout overwrites xn
  k_proj<<<dim3(3072), dim3(256), 0, stream>>>(projw_bf, xn, projb, x, out);
}